// Round 3
// baseline (337.760 us; speedup 1.0000x reference)
//
#include <hip/hip_runtime.h>
#include <hip/hip_bf16.h>
#include <float.h>

// z: (64, 256, 32, 32) fp32 ; emb: (1024, 256) fp32
// M = 65536 pixels, D = 256, K = 1024 codes
// out: [z_q (16777216 f)] [indices as float (65536)] [vq_loss (1)]
#define OUT_IDX_OFF 16777216
#define OUT_LOSS_OFF 16842752
// scratch inside d_out's z_q region (overwritten by k_out at the end):
// A2f bf16 (fragment-ordered): floats [0, 8388608)
// cand pairs (s,k) float2: floats [8388608, 12582912)  65536 rows x 32 slots
// gmin (int-punned f32):   floats [12582912, 13107200)
// gcnt (int):              floats [13107200, 13631488)
#define CAND_OFF 8388608
#define GMIN_OFF 12582912
#define GCNT_OFF 13107200
#define NSLOT 32
#define DELTA 2.0e-3f

typedef __attribute__((ext_vector_type(8))) short short8;
typedef __attribute__((ext_vector_type(4))) float f32x4;

static __device__ __forceinline__ unsigned short f2bf(float f) {
  union { __hip_bfloat16 h; unsigned short u; } cv;
  cv.h = __float2bfloat16(f);
  return cv.u;
}

// ---------------------------------------------------------------------------
// Fragment layouts (both arrays are OUR intermediates; we pick the layout):
//  A2f: 16B granule (slab, lane) with slab = rb*64 + wr*32 + kt*8 + ks*4 + tr,
//       lane = quad*16 + l15, holding row rb*128+wr*64+tr*16+l15,
//       d = kt*64+ks*32+quad*8 + j  (j=0..7).  => af load = 1 coalesced
//       global_load_dwordx4 per fragment, straight into MFMA operands.
//  E2f: slab = ck*64 + kt*16 + ks*8 + wc*4 + tc, same lane/j mapping with
//       code col = ck*128+wc*64+tc*16+l15.
// ---------------------------------------------------------------------------

// ---------------------------------------------------------------------------
// P1: emb -> E2f bf16 (fragment-ordered) + exact cws (reduction unchanged).
// ---------------------------------------------------------------------------
__global__ __launch_bounds__(256) void k_prep(const float* __restrict__ emb,
                                              unsigned short* __restrict__ E2,
                                              float* __restrict__ cws) {
  const int k = blockIdx.x, d = threadIdx.x;
  const float v = emb[k * 256 + d];
  __shared__ float red[256];
  __shared__ __align__(16) unsigned short row[256];
  row[d] = f2bf(v);
  red[d] = v * v;
  __syncthreads();
  for (int s = 128; s > 0; s >>= 1) {
    if (d < s) red[d] += red[d + s];
    __syncthreads();
  }
  if (d == 0) cws[k] = red[0];
  if (d < 32) {
    const int kt = d >> 3, ks = (d >> 2) & 1, quad = d & 3;
    const int ck = k >> 7, wc = (k >> 6) & 1, tc = (k >> 4) & 3, l15 = k & 15;
    const int slab = ck * 64 + kt * 16 + ks * 8 + wc * 4 + tc;
    const int d0 = kt * 64 + ks * 32 + quad * 8;
    *(short8*)&E2[(((size_t)slab << 6) + (quad << 4) + l15) << 3] =
        *(const short8*)&row[d0];
  }
}

// ---------------------------------------------------------------------------
// P2 v3: z (NCHW) -> A2f bf16 fragment-ordered. Load phase unchanged
// (coalesced float4 along hw, LDS transpose). Store phase: thread t writes
// local granules o = t and t+256 -> consecutive threads write consecutive
// 16B (perfect coalescing; better than k_cvt2's 256B-strided scatter).
// LDS reads stay <=2-way bank-aliased (free).
// ---------------------------------------------------------------------------
__global__ __launch_bounds__(256) void k_cvt3(const float* __restrict__ z,
                                              unsigned short* __restrict__ A2) {
  __shared__ float tile[64][65];
  const int t = threadIdx.x;
  const int pt = blockIdx.x >> 2, dt = blockIdx.x & 3;
  const int p0 = pt << 6, d0 = dt << 6;
  const int n = p0 >> 10, hw0 = p0 & 1023;
  const float* zb = z + (size_t)n * 262144 + (size_t)d0 * 1024 + hw0;
  const int hwl = (t & 15) << 2;
#pragma unroll
  for (int i = 0; i < 4; ++i) {
    const int dl = (t >> 4) + i * 16;
    const float4 v = *(const float4*)&zb[(size_t)dl * 1024 + hwl];
    tile[hwl + 0][dl] = v.x;
    tile[hwl + 1][dl] = v.y;
    tile[hwl + 2][dl] = v.z;
    tile[hwl + 3][dl] = v.w;
  }
  __syncthreads();
  const int rb = pt >> 1, wr = pt & 1, kt = dt;
  const size_t base_sh = ((size_t)(rb * 64 + wr * 32 + kt * 8)) << 9;  // shorts
#pragma unroll
  for (int h = 0; h < 2; ++h) {
    const int o = t + (h << 8);  // local granule 0..511
    const int l15o = o & 15, quado = (o >> 4) & 3;
    const int tro = (o >> 6) & 3, kso = o >> 8;
    const int pl = tro * 16 + l15o;
    const int dlb = kso * 32 + quado * 8;
    unsigned short tmp[8];
#pragma unroll
    for (int j = 0; j < 8; ++j) tmp[j] = f2bf(tile[pl][dlb + j]);
    *(short8*)&A2[base_sh + ((size_t)o << 3)] = *(short8*)tmp;
  }
}

// ---------------------------------------------------------------------------
// k_a: exact numpy-pairwise ||x||^2 (proven, unchanged).
// ---------------------------------------------------------------------------
__global__ __launch_bounds__(256) void k_a(const float* __restrict__ z,
                                           float* __restrict__ aws) {
#pragma clang fp contract(off)
  const int t = threadIdx.x;
  const int r = (blockIdx.x << 7) + (t & 127);
  const int h = t >> 7;
  const int n = r >> 10;
  const int hw = r & 1023;
  const float* zp = z + (size_t)n * 262144 + hw + (size_t)h * 131072;
  float acc[8];
#pragma unroll
  for (int j = 0; j < 8; ++j) {
    const float x = zp[(size_t)j * 1024];
    acc[j] = x * x;
  }
  for (int g = 1; g < 16; ++g) {
#pragma unroll
    for (int j = 0; j < 8; ++j) {
      const float x = zp[(size_t)(g * 8 + j) * 1024];
      const float p = x * x;
      acc[j] = acc[j] + p;
    }
  }
  const float s = ((acc[0] + acc[1]) + (acc[2] + acc[3])) +
                  ((acc[4] + acc[5]) + (acc[6] + acc[7]));
  __shared__ float red[256];
  red[t] = s;
  __syncthreads();
  if (t < 128) aws[(blockIdx.x << 7) + t] = red[t] + red[t + 128];
}

// ---------------------------------------------------------------------------
// k_gemm5: barrier-free direct-to-register MFMA prefilter.
//   - A2f/E2f are fragment-ordered, so every fragment is ONE coalesced
//     global_load_dwordx4 (64 lanes x 16B) straight into MFMA operands.
//   - No LDS tiles, no staging, NO BARRIERS in the main loop; 64 independent
//     loads + 128 MFMAs per wave, ILP + 12 waves/CU TLP hide L2 latency.
//   - XCD-chunked swizzle kept (ck fastest on each XCD -> A-panel L2-hot;
//     duplicate wave-pair loads mostly L1-hit).
//   - MFMA order (kt 0..3, ks 0..1, tr, tc) and operand values are identical
//     to k_gemm2/4 -> acc bits identical -> gmin/candidates bit-identical;
//     k_finish unchanged.
// ---------------------------------------------------------------------------
__global__ __launch_bounds__(256, 3) void k_gemm5(
    const unsigned short* __restrict__ A2, const unsigned short* __restrict__ E2,
    const float* __restrict__ cws, const float* __restrict__ aws,
    int* __restrict__ gmin, int* __restrict__ gcnt,
    float2* __restrict__ gcand) {
  __shared__ float a_l[128], c_l[128], rmkt[256], bmin[128];

  const int t = threadIdx.x;
  const int lane = t & 63;
  const int wave = __builtin_amdgcn_readfirstlane(t >> 6);
  const int wr = wave >> 1, wc = wave & 1;
  const int quad = lane >> 4, l15 = lane & 15;

  // XCD-chunked swizzle (grid 4096 % 8 == 0 -> bijective)
  const int bid = blockIdx.x;
  const int L = ((bid & 7) << 9) + (bid >> 3);
  const int rb = L >> 3, ck = L & 7;
  const int r0 = rb << 7, k0 = ck << 7;

  if (t < 128) {
    a_l[t] = aws[r0 + t];
    c_l[t] = cws[k0 + t];
  }

  // per-lane fragment bases (16B units)
  const short8* Ab =
      (const short8*)(A2 + (((((size_t)(rb * 64 + wr * 32)) << 6) + lane) << 3));
  const short8* Bb =
      (const short8*)(E2 + (((((size_t)(ck * 64 + wc * 4)) << 6) + lane) << 3));

  f32x4 acc[4][4];
#pragma unroll
  for (int a = 0; a < 4; ++a)
#pragma unroll
    for (int b = 0; b < 4; ++b) acc[a][b] = (f32x4)(0.0f);

#pragma unroll
  for (int kt = 0; kt < 4; ++kt) {
#pragma unroll
    for (int ks = 0; ks < 2; ++ks) {
      short8 af[4], bf[4];
#pragma unroll
      for (int tr = 0; tr < 4; ++tr)
        af[tr] = Ab[(kt * 8 + ks * 4 + tr) * 64];
#pragma unroll
      for (int tc = 0; tc < 4; ++tc)
        bf[tc] = Bb[(kt * 16 + ks * 8 + tc) * 64];
#pragma unroll
      for (int tr = 0; tr < 4; ++tr)
#pragma unroll
        for (int tc = 0; tc < 4; ++tc)
          acc[tr][tc] = __builtin_amdgcn_mfma_f32_16x16x32_bf16(
              af[tr], bf[tc], acc[tr][tc], 0, 0, 0);
    }
  }

  __syncthreads();  // a_l/c_l visible (no main-loop barriers anymore)

  // epilogue pass 1: chunk-local per-row min (verbatim k_gemm2/4)
#pragma unroll
  for (int tr = 0; tr < 4; ++tr)
#pragma unroll
    for (int rg = 0; rg < 4; ++rg) {
      const int rloc = wr * 64 + tr * 16 + quad * 4 + rg;
      const float av = a_l[rloc];
      float mn = FLT_MAX;
#pragma unroll
      for (int tc = 0; tc < 4; ++tc) {
        const int cloc = wc * 64 + tc * 16 + l15;
        const float s = av + fmaf(-2.0f, acc[tr][tc][rg], c_l[cloc]);
        mn = fminf(mn, s);
      }
      mn = fminf(mn, __shfl_xor(mn, 1));
      mn = fminf(mn, __shfl_xor(mn, 2));
      mn = fminf(mn, __shfl_xor(mn, 4));
      mn = fminf(mn, __shfl_xor(mn, 8));
      if (l15 == 0) rmkt[rloc * 2 + wc] = mn;
    }
  __syncthreads();
  if (t < 128) {
    const float m = fminf(rmkt[t * 2], rmkt[t * 2 + 1]);
    const int old = atomicMin(&gmin[r0 + t], __float_as_int(m));
    bmin[t] = fminf(m, __int_as_float(old));  // bits monotone for s>0
  }
  __syncthreads();
  // epilogue pass 2: append candidates within DELTA of tightened min
#pragma unroll
  for (int tr = 0; tr < 4; ++tr)
#pragma unroll
    for (int rg = 0; rg < 4; ++rg) {
      const int rloc = wr * 64 + tr * 16 + quad * 4 + rg;
      const float av = a_l[rloc];
      const float lim = bmin[rloc] + DELTA;
#pragma unroll
      for (int tc = 0; tc < 4; ++tc) {
        const int cloc = wc * 64 + tc * 16 + l15;
        const float s = av + fmaf(-2.0f, acc[tr][tc][rg], c_l[cloc]);
        if (s <= lim) {
          const int pos = atomicAdd(&gcnt[r0 + rloc], 1);
          if (pos < NSLOT)
            gcand[(size_t)(r0 + rloc) * NSLOT + pos] =
                make_float2(s, __int_as_float(k0 + cloc));
        }
      }
    }
}

// ---------------------------------------------------------------------------
// k_finish v2: 4 lanes per row, exact rescore chain UNCHANGED (bit-identical
// scores -> identical indices), quad shuffle-reduce with strict-< + lowest-k.
// Also accumulates vq_loss: winner's s IS ||z-e||^2 for that row.
// ---------------------------------------------------------------------------
__global__ __launch_bounds__(256) void k_finish(
    const float* __restrict__ z, const float* __restrict__ emb,
    const float* __restrict__ cws, const float* __restrict__ aws,
    const int* __restrict__ gmin, const int* __restrict__ gcnt,
    const float2* __restrict__ gcand, int* __restrict__ idxws,
    float* __restrict__ out) {
  const int tid = (blockIdx.x << 8) + threadIdx.x;
  const int r = tid >> 2, sub = tid & 3;
  const float lim = __int_as_float(gmin[r]) + DELTA;
  int m = gcnt[r];
  if (m > NSLOT) m = NSLOT;
  const int n = r >> 10, hw = r & 1023;
  const float* zp = z + (size_t)n * 262144 + hw;
  const float a = aws[r];
  float bestv = FLT_MAX;
  int besti = 0x7fffffff;
  for (int ci = sub; ci < m; ci += 4) {
    const float2 p = gcand[(size_t)r * NSLOT + ci];
    if (p.x > lim) continue;
    const int k = __float_as_int(p.y);
    const float* ep = emb + (size_t)k * 256;
    float dot = 0.0f;
#pragma unroll 8
    for (int d = 0; d < 256; ++d) dot = fmaf(zp[(size_t)d * 1024], ep[d], dot);
    float s = fmaf(-2.0f, dot, a);  // fl(a - 2*dot)
    s = s + cws[k];                 // fl(s + c)
    if (s < bestv || (s == bestv && k < besti)) {
      bestv = s;
      besti = k;
    }
  }
#pragma unroll
  for (int off = 1; off < 4; off <<= 1) {
    const float ov = __shfl_xor(bestv, off);
    const int oi = __shfl_xor(besti, off);
    if (ov < bestv || (ov == bestv && oi < besti)) {
      bestv = ov;
      besti = oi;
    }
  }
  if (sub == 0) {
    idxws[r] = besti;
    out[OUT_IDX_OFF + r] = (float)besti;
  }
  float c = (sub == 0) ? bestv : 0.0f;
#pragma unroll
  for (int off = 1; off < 64; off <<= 1) c += __shfl_xor(c, off);
  if ((threadIdx.x & 63) == 0)
    atomicAdd(&out[OUT_LOSS_OFF], c * (1.02f / 16777216.0f));
}

// ---------------------------------------------------------------------------
// k_out2: pure z_q gather-write (unchanged). Overwrites all d_out scratch.
// ---------------------------------------------------------------------------
__global__ __launch_bounds__(256) void k_out2(const float* __restrict__ emb,
                                              const int* __restrict__ idxws,
                                              float* __restrict__ out) {
  __shared__ float zq[32][257];
  __shared__ int sidx[32];
  const int t = threadIdx.x;
  const int p0 = blockIdx.x << 5;
  const int n = p0 >> 10, hw0 = p0 & 1023;
  if (t < 32) sidx[t] = idxws[p0 + t];
  __syncthreads();
#pragma unroll
  for (int it = 0; it < 8; ++it) {
    const int i = t + (it << 8);
    const int p = i >> 6;
    const int q = (i & 63) << 2;
    const float4 v = *(const float4*)&emb[(size_t)sidx[p] * 256 + q];
    zq[p][q] = v.x;
    zq[p][q + 1] = v.y;
    zq[p][q + 2] = v.z;
    zq[p][q + 3] = v.w;
  }
  __syncthreads();
  const int p = t & 31, d0 = t >> 5;
  float* ob = out + (size_t)n * 262144 + hw0 + p;
#pragma unroll
  for (int dd = 0; dd < 32; ++dd) {
    const int d = (dd << 3) + d0;
    ob[(size_t)d * 1024] = zq[p][d];
  }
}

// ---------------------------------------------------------------------------
extern "C" void kernel_launch(void* const* d_in, const int* in_sizes, int n_in,
                              void* d_out, int out_size, void* d_ws,
                              size_t ws_size, hipStream_t stream) {
  const float* z = (const float*)d_in[0];
  const float* emb = (const float*)d_in[1];
  float* out = (float*)d_out;

  // ws layout: E2f bf16 [1024*256] | cws [1024] | aws [65536] | idx [65536]
  unsigned short* E2 = (unsigned short*)d_ws;
  float* cws = (float*)(E2 + 262144);
  float* aws = cws + 1024;
  int* idxws = (int*)(aws + 65536);
  // scratch in d_out's z_q region (k_out2 overwrites it last):
  unsigned short* A2 = (unsigned short*)d_out;
  float2* gcand = (float2*)(out + CAND_OFF);
  int* gmin = (int*)(out + GMIN_OFF);
  int* gcnt = (int*)(out + GCNT_OFF);

  hipMemsetAsync((char*)d_out + (size_t)OUT_LOSS_OFF * 4, 0, 4, stream);
  hipMemsetAsync(gmin, 0x7f, 65536 * 4, stream);  // 0x7f7f7f7f ~ +inf
  hipMemsetAsync(gcnt, 0, 65536 * 4, stream);

  k_prep<<<dim3(1024), dim3(256), 0, stream>>>(emb, E2, cws);
  k_cvt3<<<dim3(4096), dim3(256), 0, stream>>>(z, A2);
  k_a<<<dim3(512), dim3(256), 0, stream>>>(z, aws);
  k_gemm5<<<dim3(4096), dim3(256), 0, stream>>>(A2, E2, cws, aws, gmin, gcnt,
                                                gcand);
  k_finish<<<dim3(1024), dim3(256), 0, stream>>>(z, emb, cws, aws, gmin, gcnt,
                                                 gcand, idxws, out);
  k_out2<<<dim3(2048), dim3(256), 0, stream>>>(emb, idxws, out);
}